// Round 1
// baseline (717.657 us; speedup 1.0000x reference)
//
#include <hip/hip_runtime.h>
#include <hip/hip_bf16.h>
#include <stdint.h>

#define B_ROWS 16384
#define D_IN   1200
#define D_PAD  1216      // 38 * 32
#define N_EXP  8
#define H_DIM  1024
#define SLOT   16384     // per-expert capacity in slot arrays
#define CAP    33792     // 264 * 128 padded-row capacity
#define N_TILES 264
#define LN_EPS 1e-5f
#define GATE_EPS 1e-6f

// ---- workspace layout (bytes) ----
#define WS_CNT       0          // 8 ints
#define WS_POFF      32         // 9 ints
#define WS_PAIRROW   128        // 8*16384 ints   = 524288
#define WS_PAIRGATE  524416     // 8*16384 floats = 524288
#define WS_PROWC     1048704    // 33792 ints     = 135168
#define WS_PGATEC    1183872    // 33792 floats   = 135168
#define WS_XG        1319040    // 33792*1216*2   = 82182144
#define WS_W1T       83501184   // 8*1024*1216*2  = 19922944
#define WS_HBUF      103424128  // 33792*1024*2   = 69206016
// total: 172630144 bytes (~165 MB)

typedef short bf16x8 __attribute__((ext_vector_type(8)));
typedef float f32x4 __attribute__((ext_vector_type(4)));

__device__ __forceinline__ void load_lds16(const void* gptr, void* ldsptr) {
    __builtin_amdgcn_global_load_lds(
        (__attribute__((address_space(1))) void*)const_cast<void*>(gptr),
        (__attribute__((address_space(3))) void*)ldsptr, 16, 0, 0);
}

// ---------------- 1. gating: fp32 logits, softmax, top-2, atomic routing ----------------
__global__ __launch_bounds__(256) void gating_kernel(
    const float* __restrict__ x, const float* __restrict__ wg,
    int* __restrict__ cnt, int* __restrict__ pairRow, float* __restrict__ pairGate)
{
    int b = blockIdx.x;
    int tid = threadIdx.x;
    const float* xr = x + (long)b * D_IN;

    float acc[N_EXP];
#pragma unroll
    for (int e = 0; e < N_EXP; ++e) acc[e] = 0.f;

    for (int d = tid; d < D_IN; d += 256) {
        float xv = xr[d];
        const float* w = wg + d * N_EXP;
#pragma unroll
        for (int e = 0; e < N_EXP; ++e) acc[e] += xv * w[e];
    }

    __shared__ float red[256][N_EXP];
#pragma unroll
    for (int e = 0; e < N_EXP; ++e) red[tid][e] = acc[e];
    __syncthreads();
    for (int s = 128; s > 0; s >>= 1) {
        if (tid < s) {
#pragma unroll
            for (int e = 0; e < N_EXP; ++e) red[tid][e] += red[tid + s][e];
        }
        __syncthreads();
    }

    if (tid == 0) {
        float l[N_EXP];
#pragma unroll
        for (int e = 0; e < N_EXP; ++e) l[e] = red[0][e];
        float m = l[0];
#pragma unroll
        for (int e = 1; e < N_EXP; ++e) m = fmaxf(m, l[e]);
        float p[N_EXP], s = 0.f;
#pragma unroll
        for (int e = 0; e < N_EXP; ++e) { p[e] = expf(l[e] - m); s += p[e]; }
        // top-2 (strict > keeps lowest index on ties, matching jax.lax.top_k)
        int i0 = 0;
#pragma unroll
        for (int e = 1; e < N_EXP; ++e) if (p[e] > p[i0]) i0 = e;
        int i1 = (i0 == 0) ? 1 : 0;
#pragma unroll
        for (int e = 0; e < N_EXP; ++e) if (e != i0 && p[e] > p[i1]) i1 = e;
        float v0 = p[i0] / s, v1 = p[i1] / s;
        float inv = 1.f / (v0 + v1 + GATE_EPS);
        float g0 = v0 * inv, g1 = v1 * inv;
        int s0 = atomicAdd(&cnt[i0], 1);
        pairRow[i0 * SLOT + s0] = b; pairGate[i0 * SLOT + s0] = g0;
        int s1 = atomicAdd(&cnt[i1], 1);
        pairRow[i1 * SLOT + s1] = b; pairGate[i1 * SLOT + s1] = g1;
    }
}

// ---------------- 2. prefix sum to 128-padded per-expert offsets ----------------
__global__ void offsets_kernel(const int* __restrict__ cnt, int* __restrict__ poff)
{
    if (threadIdx.x == 0 && blockIdx.x == 0) {
        int o = 0;
        for (int e = 0; e < N_EXP; ++e) {
            poff[e] = o;
            o += (cnt[e] + 127) & ~127;
        }
        poff[N_EXP] = o;
    }
}

// ---------------- 3. gather selected rows into bf16 xg (K zero-padded) ----------------
__global__ __launch_bounds__(256) void gather_kernel(
    const float* __restrict__ x, const int* __restrict__ cnt, const int* __restrict__ poff,
    const int* __restrict__ pairRow, const float* __restrict__ pairGate,
    int* __restrict__ pairRowC, float* __restrict__ pairGateC,
    __hip_bfloat16* __restrict__ xg)
{
    int p = blockIdx.x;
    if (p >= poff[N_EXP]) return;
    int e = 0;
    while (e < N_EXP - 1 && p >= poff[e + 1]) ++e;
    int i = p - poff[e];
    int tid = threadIdx.x;
    __hip_bfloat16* dst = xg + (long)p * D_PAD;

    if (i < cnt[e]) {
        int row = pairRow[e * SLOT + i];
        if (tid == 0) { pairRowC[p] = row; pairGateC[p] = pairGate[e * SLOT + i]; }
        const float* xr = x + (long)row * D_IN;
        for (int d = tid; d < D_PAD; d += 256) {
            float val = (d < D_IN) ? xr[d] : 0.f;
            dst[d] = __float2bfloat16(val);
        }
    } else {
        // padding row inside expert region: zero so GEMM on it is harmless
        if (tid == 0) { pairRowC[p] = -1; pairGateC[p] = 0.f; }
        for (int d = tid; d < D_PAD; d += 256) dst[d] = __float2bfloat16(0.f);
    }
}

// ---------------- 4. W1 [E][D][H] fp32 -> w1t [E][H][D_PAD] bf16 (LDS-tiled transpose) ----------------
__global__ __launch_bounds__(256) void w1_transpose_kernel(
    const float* __restrict__ W1, __hip_bfloat16* __restrict__ w1t)
{
    __shared__ float tile[32][33];
    int e = blockIdx.z;
    int d0 = blockIdx.x * 32;   // 38 blocks -> covers 1216
    int h0 = blockIdx.y * 32;   // 32 blocks -> 1024
    int tx = threadIdx.x;       // 0..31
    int ty = threadIdx.y;       // 0..7
    const float* src = W1 + (long)e * D_IN * H_DIM;
#pragma unroll
    for (int s = 0; s < 4; ++s) {
        int d = d0 + ty + 8 * s;
        float v = (d < D_IN) ? src[(long)d * H_DIM + h0 + tx] : 0.f;
        tile[ty + 8 * s][tx] = v;
    }
    __syncthreads();
    __hip_bfloat16* dst = w1t + (long)e * H_DIM * D_PAD;
#pragma unroll
    for (int s = 0; s < 4; ++s) {
        int h = h0 + ty + 8 * s;
        dst[(long)h * D_PAD + d0 + tx] = __float2bfloat16(tile[tx][ty + 8 * s]);
    }
}

// ---------------- 5. expert GEMM: xg[128 rows] x W1t -> h bf16 (m97 structure) ----------------
__global__ __launch_bounds__(256) void gemm_kernel(
    const __hip_bfloat16* __restrict__ xg, const __hip_bfloat16* __restrict__ w1t,
    const float* __restrict__ b1, const int* __restrict__ poff,
    __hip_bfloat16* __restrict__ hbuf)
{
    int s = blockIdx.x;
    int row0 = s * 128;
    if (row0 >= poff[N_EXP]) return;
    int e = 0;
    while (e < N_EXP - 1 && row0 >= poff[e + 1]) ++e;
    int col0 = blockIdx.y * 128;

    __shared__ short lA[128 * 32];   // [row][k] bf16
    __shared__ short lB[128 * 32];   // [col][k] bf16

    int t = threadIdx.x;
    int lane = t & 63, w = t >> 6;
    int wm = (w >> 1) * 64, wn = (w & 1) * 64;
    int l15 = lane & 15, quad = lane >> 4;

    f32x4 acc[4][4];
#pragma unroll
    for (int i = 0; i < 4; ++i)
#pragma unroll
        for (int j = 0; j < 4; ++j) acc[i][j] = (f32x4){0.f, 0.f, 0.f, 0.f};

    const __hip_bfloat16* Ab = xg + (long)row0 * D_PAD;
    const __hip_bfloat16* Bb = w1t + (long)e * H_DIM * D_PAD + (long)col0 * D_PAD;

    int r1 = t >> 2, seg = t & 3;            // staging: row r1 / r1+64, 8-elem segment
    long aoff1 = (long)r1 * D_PAD + seg * 8;
    long aoff2 = (long)(r1 + 64) * D_PAD + seg * 8;
    char* lAc = (char*)lA;
    char* lBc = (char*)lB;

    for (int kt = 0; kt < D_PAD / 32; ++kt) {
        __syncthreads();
        int k0 = kt * 32;
        load_lds16(Ab + aoff1 + k0, lAc + t * 16);
        load_lds16(Ab + aoff2 + k0, lAc + t * 16 + 4096);
        load_lds16(Bb + aoff1 + k0, lBc + t * 16);
        load_lds16(Bb + aoff2 + k0, lBc + t * 16 + 4096);
        __syncthreads();

        bf16x8 af[4], bfr[4];
#pragma unroll
        for (int i = 0; i < 4; ++i)
            af[i] = *(const bf16x8*)(lAc + (wm + i * 16 + l15) * 64 + quad * 16);
#pragma unroll
        for (int j = 0; j < 4; ++j)
            bfr[j] = *(const bf16x8*)(lBc + (wn + j * 16 + l15) * 64 + quad * 16);
#pragma unroll
        for (int i = 0; i < 4; ++i)
#pragma unroll
            for (int j = 0; j < 4; ++j)
                acc[i][j] = __builtin_amdgcn_mfma_f32_16x16x32_bf16(af[i], bfr[j], acc[i][j], 0, 0, 0);
    }

    // epilogue: + b1, store bf16 h
#pragma unroll
    for (int i = 0; i < 4; ++i) {
        int lr = wm + i * 16 + quad * 4;
#pragma unroll
        for (int j = 0; j < 4; ++j) {
            int gc = col0 + wn + j * 16 + l15;
            float bias = b1[e * H_DIM + gc];
#pragma unroll
            for (int r = 0; r < 4; ++r) {
                float v = acc[i][j][r] + bias;
                hbuf[(long)(row0 + lr + r) * H_DIM + gc] = __float2bfloat16(v);
            }
        }
    }
}

// ---------------- 6. LayerNorm + ReLU + head dot + sigmoid + gated combine ----------------
__global__ __launch_bounds__(256) void ln_head_kernel(
    const __hip_bfloat16* __restrict__ hbuf, const int* __restrict__ cnt, const int* __restrict__ poff,
    const int* __restrict__ pairRowC, const float* __restrict__ pairGateC,
    const float* __restrict__ g1, const float* __restrict__ be1,
    const float* __restrict__ W2, const float* __restrict__ b2,
    float* __restrict__ y)
{
    int p = blockIdx.x;
    if (p >= poff[N_EXP]) return;
    int e = 0;
    while (e < N_EXP - 1 && p >= poff[e + 1]) ++e;
    if (p - poff[e] >= cnt[e]) return;   // padding row

    int row = pairRowC[p];
    float gate = pairGateC[p];
    int tid = threadIdx.x;
    int w = tid >> 6;
    const __hip_bfloat16* hr = hbuf + (long)p * H_DIM;

    float v[4];
    float sum = 0.f, sumsq = 0.f;
#pragma unroll
    for (int k = 0; k < 4; ++k) {
        v[k] = __bfloat162float(hr[tid + k * 256]);
        sum += v[k];
        sumsq += v[k] * v[k];
    }
#pragma unroll
    for (int off = 32; off > 0; off >>= 1) {
        sum += __shfl_down(sum, off);
        sumsq += __shfl_down(sumsq, off);
    }
    __shared__ float rs[4], rq[4];
    if ((tid & 63) == 0) { rs[w] = sum; rq[w] = sumsq; }
    __syncthreads();
    float tot = rs[0] + rs[1] + rs[2] + rs[3];
    float totq = rq[0] + rq[1] + rq[2] + rq[3];
    float mu = tot * (1.f / H_DIM);
    float var = totq * (1.f / H_DIM) - mu * mu;
    float rstd = rsqrtf(var + LN_EPS);

    float z = 0.f;
#pragma unroll
    for (int k = 0; k < 4; ++k) {
        int h = tid + k * 256;
        float hn = (v[k] - mu) * rstd * g1[e * H_DIM + h] + be1[e * H_DIM + h];
        hn = fmaxf(hn, 0.f);
        z += hn * W2[e * H_DIM + h];
    }
#pragma unroll
    for (int off = 32; off > 0; off >>= 1) z += __shfl_down(z, off);
    __syncthreads();                        // rs reuse
    if ((tid & 63) == 0) rs[w] = z;
    __syncthreads();
    if (tid == 0) {
        float zt = rs[0] + rs[1] + rs[2] + rs[3] + b2[e];
        float o = 1.f / (1.f + expf(-zt));
        atomicAdd(&y[row], gate * o);
    }
}

extern "C" void kernel_launch(void* const* d_in, const int* in_sizes, int n_in,
                              void* d_out, int out_size, void* d_ws, size_t ws_size,
                              hipStream_t stream)
{
    const float* x   = (const float*)d_in[0];
    const float* wg  = (const float*)d_in[1];
    const float* W1  = (const float*)d_in[2];
    const float* b1  = (const float*)d_in[3];
    const float* g1  = (const float*)d_in[4];
    const float* be1 = (const float*)d_in[5];
    const float* W2  = (const float*)d_in[6];
    const float* b2  = (const float*)d_in[7];
    float* y = (float*)d_out;

    char* ws = (char*)d_ws;
    int*   cnt       = (int*)(ws + WS_CNT);
    int*   poff      = (int*)(ws + WS_POFF);
    int*   pairRow   = (int*)(ws + WS_PAIRROW);
    float* pairGate  = (float*)(ws + WS_PAIRGATE);
    int*   pairRowC  = (int*)(ws + WS_PROWC);
    float* pairGateC = (float*)(ws + WS_PGATEC);
    __hip_bfloat16* xg   = (__hip_bfloat16*)(ws + WS_XG);
    __hip_bfloat16* w1t  = (__hip_bfloat16*)(ws + WS_W1T);
    __hip_bfloat16* hbuf = (__hip_bfloat16*)(ws + WS_HBUF);

    hipMemsetAsync(cnt, 0, 8 * sizeof(int), stream);
    hipMemsetAsync(y, 0, (size_t)out_size * sizeof(float), stream);

    gating_kernel<<<B_ROWS, 256, 0, stream>>>(x, wg, cnt, pairRow, pairGate);
    offsets_kernel<<<1, 64, 0, stream>>>(cnt, poff);
    w1_transpose_kernel<<<dim3(38, 32, 8), dim3(32, 8), 0, stream>>>(W1, w1t);
    gather_kernel<<<CAP, 256, 0, stream>>>(x, cnt, poff, pairRow, pairGate,
                                           pairRowC, pairGateC, xg);
    gemm_kernel<<<dim3(N_TILES, 8), 256, 0, stream>>>(xg, w1t, b1, poff, hbuf);
    ln_head_kernel<<<CAP, 256, 0, stream>>>(hbuf, cnt, poff, pairRowC, pairGateC,
                                            g1, be1, W2, b2, y);
}

// Round 2
// 712.169 us; speedup vs baseline: 1.0077x; 1.0077x over previous
//
#include <hip/hip_runtime.h>
#include <hip/hip_bf16.h>
#include <stdint.h>

#define B_ROWS 16384
#define D_IN   1200
#define D_PAD  1216      // 38 * 32
#define N_EXP  8
#define H_DIM  1024
#define SLOT   16384     // per-expert capacity in slot arrays
#define CAP    33792     // 264 * 128 padded-row capacity
#define N_TILES 264
#define LN_EPS 1e-5f
#define GATE_EPS 1e-6f

// ---- workspace layout (bytes) ----
#define WS_CNT       0          // 8 ints
#define WS_POFF      32         // 9 ints
#define WS_PAIRROW   128        // 8*16384 ints   = 524288
#define WS_PAIRGATE  524416     // 8*16384 floats = 524288
#define WS_PROWC     1048704    // 33792 ints     = 135168
#define WS_PGATEC    1183872    // 33792 floats   = 135168
#define WS_XG        1319040    // 33792*1216*2   = 82182144
#define WS_W1T       83501184   // 8*1024*1216*2  = 19922944
#define WS_HBUF      103424128  // 33792*1024*2   = 69206016
// total: 172630144 bytes (~165 MB)

typedef short bf16x8 __attribute__((ext_vector_type(8)));
typedef short short8 __attribute__((ext_vector_type(8)));
typedef short short4v __attribute__((ext_vector_type(4)));
typedef float f32x4 __attribute__((ext_vector_type(4)));

__device__ __forceinline__ void load_lds16(const void* gptr, void* ldsptr) {
    __builtin_amdgcn_global_load_lds(
        (__attribute__((address_space(1))) void*)const_cast<void*>(gptr),
        (__attribute__((address_space(3))) void*)ldsptr, 16, 0, 0);
}

__device__ __forceinline__ short8 pack_bf16x8(float4 a, float4 b) {
    union { short8 v; __hip_bfloat16 h[8]; } u;
    u.h[0] = __float2bfloat16(a.x); u.h[1] = __float2bfloat16(a.y);
    u.h[2] = __float2bfloat16(a.z); u.h[3] = __float2bfloat16(a.w);
    u.h[4] = __float2bfloat16(b.x); u.h[5] = __float2bfloat16(b.y);
    u.h[6] = __float2bfloat16(b.z); u.h[7] = __float2bfloat16(b.w);
    return u.v;
}

// ---------------- 1. gating: wave-per-row, fp32, butterfly reduce ----------------
__global__ __launch_bounds__(256) void gating_kernel(
    const float* __restrict__ x, const float* __restrict__ wg,
    int* __restrict__ cnt, int* __restrict__ pairRow, float* __restrict__ pairGate)
{
    int row = blockIdx.x * 4 + (threadIdx.x >> 6);
    int lane = threadIdx.x & 63;
    const float4* xr = (const float4*)(x + (long)row * D_IN);   // 300 float4

    float acc[N_EXP];
#pragma unroll
    for (int e = 0; e < N_EXP; ++e) acc[e] = 0.f;

    for (int i = lane; i < 300; i += 64) {
        float4 xv = xr[i];
        const float4* w = (const float4*)(wg + (long)i * 32);   // 4 d-rows x 8 experts
        float4 w0 = w[0], w1 = w[1];   // d+0
        float4 w2 = w[2], w3 = w[3];   // d+1
        float4 w4 = w[4], w5 = w[5];   // d+2
        float4 w6 = w[6], w7 = w[7];   // d+3
        acc[0] += xv.x * w0.x + xv.y * w2.x + xv.z * w4.x + xv.w * w6.x;
        acc[1] += xv.x * w0.y + xv.y * w2.y + xv.z * w4.y + xv.w * w6.y;
        acc[2] += xv.x * w0.z + xv.y * w2.z + xv.z * w4.z + xv.w * w6.z;
        acc[3] += xv.x * w0.w + xv.y * w2.w + xv.z * w4.w + xv.w * w6.w;
        acc[4] += xv.x * w1.x + xv.y * w3.x + xv.z * w5.x + xv.w * w7.x;
        acc[5] += xv.x * w1.y + xv.y * w3.y + xv.z * w5.y + xv.w * w7.y;
        acc[6] += xv.x * w1.z + xv.y * w3.z + xv.z * w5.z + xv.w * w7.z;
        acc[7] += xv.x * w1.w + xv.y * w3.w + xv.z * w5.w + xv.w * w7.w;
    }

#pragma unroll
    for (int e = 0; e < N_EXP; ++e) {
        float v = acc[e];
#pragma unroll
        for (int off = 32; off > 0; off >>= 1) v += __shfl_xor(v, off, 64);
        acc[e] = v;
    }

    if (lane == 0) {
        float m = acc[0];
#pragma unroll
        for (int e = 1; e < N_EXP; ++e) m = fmaxf(m, acc[e]);
        float p[N_EXP], s = 0.f;
#pragma unroll
        for (int e = 0; e < N_EXP; ++e) { p[e] = expf(acc[e] - m); s += p[e]; }
        int i0 = 0;
#pragma unroll
        for (int e = 1; e < N_EXP; ++e) if (p[e] > p[i0]) i0 = e;
        int i1 = (i0 == 0) ? 1 : 0;
#pragma unroll
        for (int e = 0; e < N_EXP; ++e) if (e != i0 && p[e] > p[i1]) i1 = e;
        float v0 = p[i0] / s, v1 = p[i1] / s;
        float inv = 1.f / (v0 + v1 + GATE_EPS);
        float g0 = v0 * inv, g1 = v1 * inv;
        int s0 = atomicAdd(&cnt[i0], 1);
        pairRow[i0 * SLOT + s0] = row; pairGate[i0 * SLOT + s0] = g0;
        int s1 = atomicAdd(&cnt[i1], 1);
        pairRow[i1 * SLOT + s1] = row; pairGate[i1 * SLOT + s1] = g1;
    }
}

// ---------------- 2. prefix sum to 128-padded per-expert offsets ----------------
__global__ void offsets_kernel(const int* __restrict__ cnt, int* __restrict__ poff)
{
    if (threadIdx.x == 0 && blockIdx.x == 0) {
        int o = 0;
        for (int e = 0; e < N_EXP; ++e) {
            poff[e] = o;
            o += (cnt[e] + 127) & ~127;
        }
        poff[N_EXP] = o;
    }
}

// ---------------- 3. gather selected rows into bf16 xg (vectorized 16B stores) ----------------
__global__ __launch_bounds__(256) void gather_kernel(
    const float* __restrict__ x, const int* __restrict__ cnt, const int* __restrict__ poff,
    const int* __restrict__ pairRow, const float* __restrict__ pairGate,
    int* __restrict__ pairRowC, float* __restrict__ pairGateC,
    __hip_bfloat16* __restrict__ xg)
{
    int p = blockIdx.x;
    if (p >= poff[N_EXP]) return;
    int e = 0;
    while (e < N_EXP - 1 && p >= poff[e + 1]) ++e;
    int i = p - poff[e];
    int tid = threadIdx.x;
    short8* dst = (short8*)(xg + (long)p * D_PAD);   // 152 chunks of 8 bf16

    if (i < cnt[e]) {
        int row = pairRow[e * SLOT + i];
        if (tid == 0) { pairRowC[p] = row; pairGateC[p] = pairGate[e * SLOT + i]; }
        if (tid < 152) {
            short8 out;
            if (tid < 150) {   // 150*8 = 1200 real elements
                const float4* src = (const float4*)(x + (long)row * D_IN) + tid * 2;
                out = pack_bf16x8(src[0], src[1]);
            } else {
                out = (short8){0,0,0,0,0,0,0,0};
            }
            dst[tid] = out;
        }
    } else {
        if (tid == 0) { pairRowC[p] = -1; pairGateC[p] = 0.f; }
        if (tid < 152) dst[tid] = (short8){0,0,0,0,0,0,0,0};
    }
}

// ---------------- 4. W1 [E][D][H] fp32 -> w1t [E][H][D_PAD] bf16 (LDS-tiled transpose) ----------------
__global__ __launch_bounds__(256) void w1_transpose_kernel(
    const float* __restrict__ W1, __hip_bfloat16* __restrict__ w1t)
{
    __shared__ float tile[32][33];
    int e = blockIdx.z;
    int d0 = blockIdx.x * 32;   // 38 blocks -> covers 1216
    int h0 = blockIdx.y * 32;   // 32 blocks -> 1024
    int tx = threadIdx.x;       // 0..31
    int ty = threadIdx.y;       // 0..7
    const float* src = W1 + (long)e * D_IN * H_DIM;
#pragma unroll
    for (int s = 0; s < 4; ++s) {
        int d = d0 + ty + 8 * s;
        float v = (d < D_IN) ? src[(long)d * H_DIM + h0 + tx] : 0.f;
        tile[ty + 8 * s][tx] = v;
    }
    __syncthreads();
    __hip_bfloat16* dst = w1t + (long)e * H_DIM * D_PAD;
#pragma unroll
    for (int s = 0; s < 4; ++s) {
        int h = h0 + ty + 8 * s;
        dst[(long)h * D_PAD + d0 + tx] = __float2bfloat16(tile[tx][ty + 8 * s]);
    }
}

// ---------------- 5. expert GEMM: xg[128 rows] x W1t -> h bf16 (m97 structure) ----------------
__global__ __launch_bounds__(256) void gemm_kernel(
    const __hip_bfloat16* __restrict__ xg, const __hip_bfloat16* __restrict__ w1t,
    const float* __restrict__ b1, const int* __restrict__ poff,
    __hip_bfloat16* __restrict__ hbuf)
{
    int s = blockIdx.x;
    int row0 = s * 128;
    if (row0 >= poff[N_EXP]) return;
    int e = 0;
    while (e < N_EXP - 1 && row0 >= poff[e + 1]) ++e;
    int col0 = blockIdx.y * 128;

    __shared__ short lA[128 * 32];   // [row][k] bf16
    __shared__ short lB[128 * 32];   // [col][k] bf16

    int t = threadIdx.x;
    int lane = t & 63, w = t >> 6;
    int wm = (w >> 1) * 64, wn = (w & 1) * 64;
    int l15 = lane & 15, quad = lane >> 4;

    f32x4 acc[4][4];
#pragma unroll
    for (int i = 0; i < 4; ++i)
#pragma unroll
        for (int j = 0; j < 4; ++j) acc[i][j] = (f32x4){0.f, 0.f, 0.f, 0.f};

    const __hip_bfloat16* Ab = xg + (long)row0 * D_PAD;
    const __hip_bfloat16* Bb = w1t + (long)e * H_DIM * D_PAD + (long)col0 * D_PAD;

    int r1 = t >> 2, seg = t & 3;            // staging: row r1 / r1+64, 8-elem segment
    long aoff1 = (long)r1 * D_PAD + seg * 8;
    long aoff2 = (long)(r1 + 64) * D_PAD + seg * 8;
    char* lAc = (char*)lA;
    char* lBc = (char*)lB;

    for (int kt = 0; kt < D_PAD / 32; ++kt) {
        __syncthreads();
        int k0 = kt * 32;
        load_lds16(Ab + aoff1 + k0, lAc + t * 16);
        load_lds16(Ab + aoff2 + k0, lAc + t * 16 + 4096);
        load_lds16(Bb + aoff1 + k0, lBc + t * 16);
        load_lds16(Bb + aoff2 + k0, lBc + t * 16 + 4096);
        __syncthreads();

        bf16x8 af[4], bfr[4];
#pragma unroll
        for (int i = 0; i < 4; ++i)
            af[i] = *(const bf16x8*)(lAc + (wm + i * 16 + l15) * 64 + quad * 16);
#pragma unroll
        for (int j = 0; j < 4; ++j)
            bfr[j] = *(const bf16x8*)(lBc + (wn + j * 16 + l15) * 64 + quad * 16);
#pragma unroll
        for (int i = 0; i < 4; ++i)
#pragma unroll
            for (int j = 0; j < 4; ++j)
                acc[i][j] = __builtin_amdgcn_mfma_f32_16x16x32_bf16(af[i], bfr[j], acc[i][j], 0, 0, 0);
    }

    // epilogue: + b1, store bf16 h
#pragma unroll
    for (int i = 0; i < 4; ++i) {
        int lr = wm + i * 16 + quad * 4;
#pragma unroll
        for (int j = 0; j < 4; ++j) {
            int gc = col0 + wn + j * 16 + l15;
            float bias = b1[e * H_DIM + gc];
#pragma unroll
            for (int r = 0; r < 4; ++r) {
                float v = acc[i][j][r] + bias;
                hbuf[(long)(row0 + lr + r) * H_DIM + gc] = __float2bfloat16(v);
            }
        }
    }
}

// ---------------- 6. LayerNorm + ReLU + head dot + sigmoid + gated combine ----------------
__global__ __launch_bounds__(256) void ln_head_kernel(
    const __hip_bfloat16* __restrict__ hbuf, const int* __restrict__ cnt, const int* __restrict__ poff,
    const int* __restrict__ pairRowC, const float* __restrict__ pairGateC,
    const float* __restrict__ g1, const float* __restrict__ be1,
    const float* __restrict__ W2, const float* __restrict__ b2,
    float* __restrict__ y)
{
    int p = blockIdx.x;
    if (p >= poff[N_EXP]) return;
    int e = 0;
    while (e < N_EXP - 1 && p >= poff[e + 1]) ++e;
    if (p - poff[e] >= cnt[e]) return;   // padding row

    int row = pairRowC[p];
    float gate = pairGateC[p];
    int tid = threadIdx.x;
    int w = tid >> 6;
    const __hip_bfloat16* hr = hbuf + (long)p * H_DIM;

    // each thread owns 4 consecutive h elements: [tid*4 .. tid*4+3]
    union { short4v s; __hip_bfloat16 h[4]; } hv;
    hv.s = ((const short4v*)hr)[tid];
    float v[4];
    float sum = 0.f, sumsq = 0.f;
#pragma unroll
    for (int k = 0; k < 4; ++k) {
        v[k] = __bfloat162float(hv.h[k]);
        sum += v[k];
        sumsq += v[k] * v[k];
    }
#pragma unroll
    for (int off = 32; off > 0; off >>= 1) {
        sum += __shfl_down(sum, off);
        sumsq += __shfl_down(sumsq, off);
    }
    __shared__ float rs[4], rq[4];
    if ((tid & 63) == 0) { rs[w] = sum; rq[w] = sumsq; }
    __syncthreads();
    float tot = rs[0] + rs[1] + rs[2] + rs[3];
    float totq = rq[0] + rq[1] + rq[2] + rq[3];
    float mu = tot * (1.f / H_DIM);
    float var = totq * (1.f / H_DIM) - mu * mu;
    float rstd = rsqrtf(var + LN_EPS);

    float4 gv = ((const float4*)(g1 + e * H_DIM))[tid];
    float4 bv = ((const float4*)(be1 + e * H_DIM))[tid];
    float4 wv = ((const float4*)(W2 + e * H_DIM))[tid];
    float z = 0.f;
    {
        float hn0 = fmaxf((v[0] - mu) * rstd * gv.x + bv.x, 0.f);
        float hn1 = fmaxf((v[1] - mu) * rstd * gv.y + bv.y, 0.f);
        float hn2 = fmaxf((v[2] - mu) * rstd * gv.z + bv.z, 0.f);
        float hn3 = fmaxf((v[3] - mu) * rstd * gv.w + bv.w, 0.f);
        z = hn0 * wv.x + hn1 * wv.y + hn2 * wv.z + hn3 * wv.w;
    }
#pragma unroll
    for (int off = 32; off > 0; off >>= 1) z += __shfl_down(z, off);
    __syncthreads();                        // rs reuse
    if ((tid & 63) == 0) rs[w] = z;
    __syncthreads();
    if (tid == 0) {
        float zt = rs[0] + rs[1] + rs[2] + rs[3] + b2[e];
        float o = 1.f / (1.f + expf(-zt));
        atomicAdd(&y[row], gate * o);
    }
}

extern "C" void kernel_launch(void* const* d_in, const int* in_sizes, int n_in,
                              void* d_out, int out_size, void* d_ws, size_t ws_size,
                              hipStream_t stream)
{
    const float* x   = (const float*)d_in[0];
    const float* wg  = (const float*)d_in[1];
    const float* W1  = (const float*)d_in[2];
    const float* b1  = (const float*)d_in[3];
    const float* g1  = (const float*)d_in[4];
    const float* be1 = (const float*)d_in[5];
    const float* W2  = (const float*)d_in[6];
    const float* b2  = (const float*)d_in[7];
    float* y = (float*)d_out;

    char* ws = (char*)d_ws;
    int*   cnt       = (int*)(ws + WS_CNT);
    int*   poff      = (int*)(ws + WS_POFF);
    int*   pairRow   = (int*)(ws + WS_PAIRROW);
    float* pairGate  = (float*)(ws + WS_PAIRGATE);
    int*   pairRowC  = (int*)(ws + WS_PROWC);
    float* pairGateC = (float*)(ws + WS_PGATEC);
    __hip_bfloat16* xg   = (__hip_bfloat16*)(ws + WS_XG);
    __hip_bfloat16* w1t  = (__hip_bfloat16*)(ws + WS_W1T);
    __hip_bfloat16* hbuf = (__hip_bfloat16*)(ws + WS_HBUF);

    hipMemsetAsync(cnt, 0, 8 * sizeof(int), stream);
    hipMemsetAsync(y, 0, (size_t)out_size * sizeof(float), stream);

    gating_kernel<<<B_ROWS / 4, 256, 0, stream>>>(x, wg, cnt, pairRow, pairGate);
    offsets_kernel<<<1, 64, 0, stream>>>(cnt, poff);
    w1_transpose_kernel<<<dim3(38, 32, 8), dim3(32, 8), 0, stream>>>(W1, w1t);
    gather_kernel<<<CAP, 256, 0, stream>>>(x, cnt, poff, pairRow, pairGate,
                                           pairRowC, pairGateC, xg);
    gemm_kernel<<<dim3(N_TILES, 8), 256, 0, stream>>>(xg, w1t, b1, poff, hbuf);
    ln_head_kernel<<<CAP, 256, 0, stream>>>(hbuf, cnt, poff, pairRowC, pairGateC,
                                            g1, be1, W2, b2, y);
}

// Round 3
// 407.143 us; speedup vs baseline: 1.7627x; 1.7492x over previous
//
#include <hip/hip_runtime.h>
#include <hip/hip_bf16.h>
#include <stdint.h>

#define B_ROWS 16384
#define D_IN   1200
#define D_PAD  1216      // 38 * 32
#define N_EXP  8
#define H_DIM  1024
#define CAP    33792     // 264 * 128 padded-row capacity
#define N_TILES 264
#define LN_EPS 1e-5f
#define GATE_EPS 1e-6f
#define CNT_STRIDE 16    // pad expert counters to separate 64B cache lines

// ---- workspace layout (bytes) ----
#define WS_CNT       0          // 8 counters @ stride 16 ints = 512 B
#define WS_CNT2      576        // second padded counter set (scatter) = 512 B
#define WS_POFF      512        // 9 ints (in the gap; 64 B reserved at 512.. wait see below)
// NOTE: layout recomputed below to avoid overlap:
//   cnt   : [0, 512)
//   poff  : [512, 576)
//   cnt2  : [576, 1088)
//   topIdx: [1088, 132160)      16384*2 ints
//   topGate:[132160, 263232)    16384*2 floats
//   prowC : [263232, 398400)    33792 ints
//   pgateC: [398400, 533568)    33792 floats
//   xg    : [533568, 82715712)  33792*1216*2
//   w1t   : [82715712, 102638656) 8*1024*1216*2
//   hbuf  : [102638656, 171844672) 33792*1024*2   (~164 MB total)
#define O_CNT    0
#define O_POFF   512
#define O_CNT2   576
#define O_TOPI   1088
#define O_TOPG   132160
#define O_PROWC  263232
#define O_PGATEC 398400
#define O_XG     533568
#define O_W1T    82715712
#define O_HBUF   102638656

typedef short bf16x8 __attribute__((ext_vector_type(8)));
typedef short short8 __attribute__((ext_vector_type(8)));
typedef short short4v __attribute__((ext_vector_type(4)));
typedef float f32x4 __attribute__((ext_vector_type(4)));

__device__ __forceinline__ void load_lds16(const void* gptr, void* ldsptr) {
    __builtin_amdgcn_global_load_lds(
        (__attribute__((address_space(1))) void*)const_cast<void*>(gptr),
        (__attribute__((address_space(3))) void*)ldsptr, 16, 0, 0);
}

__device__ __forceinline__ short8 pack_bf16x8(float4 a, float4 b) {
    union { short8 v; __hip_bfloat16 h[8]; } u;
    u.h[0] = __float2bfloat16(a.x); u.h[1] = __float2bfloat16(a.y);
    u.h[2] = __float2bfloat16(a.z); u.h[3] = __float2bfloat16(a.w);
    u.h[4] = __float2bfloat16(b.x); u.h[5] = __float2bfloat16(b.y);
    u.h[6] = __float2bfloat16(b.z); u.h[7] = __float2bfloat16(b.w);
    return u.v;
}

// ---------------- 1. gating: wave-per-row, fp32, dense top-2 output (NO atomics) ----------------
__global__ __launch_bounds__(256) void gating_kernel(
    const float* __restrict__ x, const float* __restrict__ wg,
    int* __restrict__ topIdx, float* __restrict__ topGate)
{
    int row = blockIdx.x * 4 + (threadIdx.x >> 6);
    int lane = threadIdx.x & 63;
    const float4* xr = (const float4*)(x + (long)row * D_IN);   // 300 float4

    float acc[N_EXP];
#pragma unroll
    for (int e = 0; e < N_EXP; ++e) acc[e] = 0.f;

    for (int i = lane; i < 300; i += 64) {
        float4 xv = xr[i];
        const float4* w = (const float4*)(wg + (long)i * 32);   // 4 d-rows x 8 experts
        float4 w0 = w[0], w1 = w[1];
        float4 w2 = w[2], w3 = w[3];
        float4 w4 = w[4], w5 = w[5];
        float4 w6 = w[6], w7 = w[7];
        acc[0] += xv.x * w0.x + xv.y * w2.x + xv.z * w4.x + xv.w * w6.x;
        acc[1] += xv.x * w0.y + xv.y * w2.y + xv.z * w4.y + xv.w * w6.y;
        acc[2] += xv.x * w0.z + xv.y * w2.z + xv.z * w4.z + xv.w * w6.z;
        acc[3] += xv.x * w0.w + xv.y * w2.w + xv.z * w4.w + xv.w * w6.w;
        acc[4] += xv.x * w1.x + xv.y * w3.x + xv.z * w5.x + xv.w * w7.x;
        acc[5] += xv.x * w1.y + xv.y * w3.y + xv.z * w5.y + xv.w * w7.y;
        acc[6] += xv.x * w1.z + xv.y * w3.z + xv.z * w5.z + xv.w * w7.z;
        acc[7] += xv.x * w1.w + xv.y * w3.w + xv.z * w5.w + xv.w * w7.w;
    }

#pragma unroll
    for (int e = 0; e < N_EXP; ++e) {
        float v = acc[e];
#pragma unroll
        for (int off = 32; off > 0; off >>= 1) v += __shfl_xor(v, off, 64);
        acc[e] = v;
    }

    if (lane == 0) {
        float m = acc[0];
#pragma unroll
        for (int e = 1; e < N_EXP; ++e) m = fmaxf(m, acc[e]);
        float p[N_EXP], s = 0.f;
#pragma unroll
        for (int e = 0; e < N_EXP; ++e) { p[e] = expf(acc[e] - m); s += p[e]; }
        int i0 = 0;
#pragma unroll
        for (int e = 1; e < N_EXP; ++e) if (p[e] > p[i0]) i0 = e;
        int i1 = (i0 == 0) ? 1 : 0;
#pragma unroll
        for (int e = 0; e < N_EXP; ++e) if (e != i0 && p[e] > p[i1]) i1 = e;
        float v0 = p[i0] / s, v1 = p[i1] / s;
        float inv = 1.f / (v0 + v1 + GATE_EPS);
        ((int2*)topIdx)[row] = make_int2(i0, i1);
        ((float2*)topGate)[row] = make_float2(v0 * inv, v1 * inv);
    }
}

// ---------------- 2a. histogram: LDS-aggregated, 8 padded global atomics/block ----------------
__global__ __launch_bounds__(256) void hist_kernel(
    const int* __restrict__ topIdx, int* __restrict__ cnt)
{
    __shared__ int lcnt[N_EXP];
    int tid = threadIdx.x;
    if (tid < N_EXP) lcnt[tid] = 0;
    __syncthreads();
    int row = blockIdx.x * 256 + tid;
    int2 e = ((const int2*)topIdx)[row];
    atomicAdd(&lcnt[e.x], 1);
    atomicAdd(&lcnt[e.y], 1);
    __syncthreads();
    if (tid < N_EXP) atomicAdd(&cnt[tid * CNT_STRIDE], lcnt[tid]);
}

// ---------------- 2b. prefix sum to 128-padded per-expert offsets ----------------
__global__ void offsets_kernel(const int* __restrict__ cnt, int* __restrict__ poff)
{
    if (threadIdx.x == 0 && blockIdx.x == 0) {
        int o = 0;
        for (int e = 0; e < N_EXP; ++e) {
            poff[e] = o;
            o += (cnt[e * CNT_STRIDE] + 127) & ~127;
        }
        poff[N_EXP] = o;
    }
}

// ---------------- 2c. scatter rows into compact per-expert lists ----------------
__global__ __launch_bounds__(256) void scatter_kernel(
    const int* __restrict__ topIdx, const float* __restrict__ topGate,
    const int* __restrict__ poff, int* __restrict__ cnt2,
    int* __restrict__ pairRowC, float* __restrict__ pairGateC)
{
    __shared__ int lcnt[N_EXP];
    __shared__ int base[N_EXP];
    int tid = threadIdx.x;
    if (tid < N_EXP) lcnt[tid] = 0;
    __syncthreads();
    int row = blockIdx.x * 256 + tid;
    int2 e = ((const int2*)topIdx)[row];
    float2 g = ((const float2*)topGate)[row];
    int s0 = atomicAdd(&lcnt[e.x], 1);
    int s1 = atomicAdd(&lcnt[e.y], 1);
    __syncthreads();
    if (tid < N_EXP) base[tid] = atomicAdd(&cnt2[tid * CNT_STRIDE], lcnt[tid]);
    __syncthreads();
    int p0 = poff[e.x] + base[e.x] + s0;
    pairRowC[p0] = row; pairGateC[p0] = g.x;
    int p1 = poff[e.y] + base[e.y] + s1;
    pairRowC[p1] = row; pairGateC[p1] = g.y;
}

// ---------------- 3. gather selected rows into bf16 xg (vectorized 16B stores) ----------------
__global__ __launch_bounds__(256) void gather_kernel(
    const float* __restrict__ x, const int* __restrict__ cnt, const int* __restrict__ poff,
    const int* __restrict__ pairRowC, __hip_bfloat16* __restrict__ xg)
{
    int p = blockIdx.x;
    if (p >= poff[N_EXP]) return;
    int e = 0;
    while (e < N_EXP - 1 && p >= poff[e + 1]) ++e;
    int i = p - poff[e];
    int tid = threadIdx.x;
    short8* dst = (short8*)(xg + (long)p * D_PAD);   // 152 chunks of 8 bf16
    if (tid >= 152) return;

    if (i < cnt[e * CNT_STRIDE]) {
        int row = pairRowC[p];
        short8 out;
        if (tid < 150) {   // 150*8 = 1200 real elements
            const float4* src = (const float4*)(x + (long)row * D_IN) + tid * 2;
            out = pack_bf16x8(src[0], src[1]);
        } else {
            out = (short8){0,0,0,0,0,0,0,0};
        }
        dst[tid] = out;
    } else {
        dst[tid] = (short8){0,0,0,0,0,0,0,0};   // padding row: zero so GEMM is harmless
    }
}

// ---------------- 4. W1 [E][D][H] fp32 -> w1t [E][H][D_PAD] bf16 (LDS-tiled transpose) ----------------
__global__ __launch_bounds__(256) void w1_transpose_kernel(
    const float* __restrict__ W1, __hip_bfloat16* __restrict__ w1t)
{
    __shared__ float tile[32][33];
    int e = blockIdx.z;
    int d0 = blockIdx.x * 32;   // 38 blocks -> covers 1216
    int h0 = blockIdx.y * 32;   // 32 blocks -> 1024
    int tx = threadIdx.x;       // 0..31
    int ty = threadIdx.y;       // 0..7
    const float* src = W1 + (long)e * D_IN * H_DIM;
#pragma unroll
    for (int s = 0; s < 4; ++s) {
        int d = d0 + ty + 8 * s;
        float v = (d < D_IN) ? src[(long)d * H_DIM + h0 + tx] : 0.f;
        tile[ty + 8 * s][tx] = v;
    }
    __syncthreads();
    __hip_bfloat16* dst = w1t + (long)e * H_DIM * D_PAD;
#pragma unroll
    for (int s = 0; s < 4; ++s) {
        int h = h0 + ty + 8 * s;
        dst[(long)h * D_PAD + d0 + tx] = __float2bfloat16(tile[tx][ty + 8 * s]);
    }
}

// ---------------- 5. expert GEMM: xg[128 rows] x W1t -> h bf16 (m97 structure) ----------------
__global__ __launch_bounds__(256) void gemm_kernel(
    const __hip_bfloat16* __restrict__ xg, const __hip_bfloat16* __restrict__ w1t,
    const float* __restrict__ b1, const int* __restrict__ poff,
    __hip_bfloat16* __restrict__ hbuf)
{
    int s = blockIdx.x;
    int row0 = s * 128;
    if (row0 >= poff[N_EXP]) return;
    int e = 0;
    while (e < N_EXP - 1 && row0 >= poff[e + 1]) ++e;
    int col0 = blockIdx.y * 128;

    __shared__ short lA[128 * 32];   // [row][k] bf16
    __shared__ short lB[128 * 32];   // [col][k] bf16

    int t = threadIdx.x;
    int lane = t & 63, w = t >> 6;
    int wm = (w >> 1) * 64, wn = (w & 1) * 64;
    int l15 = lane & 15, quad = lane >> 4;

    f32x4 acc[4][4];
#pragma unroll
    for (int i = 0; i < 4; ++i)
#pragma unroll
        for (int j = 0; j < 4; ++j) acc[i][j] = (f32x4){0.f, 0.f, 0.f, 0.f};

    const __hip_bfloat16* Ab = xg + (long)row0 * D_PAD;
    const __hip_bfloat16* Bb = w1t + (long)e * H_DIM * D_PAD + (long)col0 * D_PAD;

    int r1 = t >> 2, seg = t & 3;
    long aoff1 = (long)r1 * D_PAD + seg * 8;
    long aoff2 = (long)(r1 + 64) * D_PAD + seg * 8;
    char* lAc = (char*)lA;
    char* lBc = (char*)lB;

    for (int kt = 0; kt < D_PAD / 32; ++kt) {
        __syncthreads();
        int k0 = kt * 32;
        load_lds16(Ab + aoff1 + k0, lAc + t * 16);
        load_lds16(Ab + aoff2 + k0, lAc + t * 16 + 4096);
        load_lds16(Bb + aoff1 + k0, lBc + t * 16);
        load_lds16(Bb + aoff2 + k0, lBc + t * 16 + 4096);
        __syncthreads();

        bf16x8 af[4], bfr[4];
#pragma unroll
        for (int i = 0; i < 4; ++i)
            af[i] = *(const bf16x8*)(lAc + (wm + i * 16 + l15) * 64 + quad * 16);
#pragma unroll
        for (int j = 0; j < 4; ++j)
            bfr[j] = *(const bf16x8*)(lBc + (wn + j * 16 + l15) * 64 + quad * 16);
#pragma unroll
        for (int i = 0; i < 4; ++i)
#pragma unroll
            for (int j = 0; j < 4; ++j)
                acc[i][j] = __builtin_amdgcn_mfma_f32_16x16x32_bf16(af[i], bfr[j], acc[i][j], 0, 0, 0);
    }

#pragma unroll
    for (int i = 0; i < 4; ++i) {
        int lr = wm + i * 16 + quad * 4;
#pragma unroll
        for (int j = 0; j < 4; ++j) {
            int gc = col0 + wn + j * 16 + l15;
            float bias = b1[e * H_DIM + gc];
#pragma unroll
            for (int r = 0; r < 4; ++r) {
                float v = acc[i][j][r] + bias;
                hbuf[(long)(row0 + lr + r) * H_DIM + gc] = __float2bfloat16(v);
            }
        }
    }
}

// ---------------- 6. LayerNorm + ReLU + head dot + sigmoid + gated combine ----------------
__global__ __launch_bounds__(256) void ln_head_kernel(
    const __hip_bfloat16* __restrict__ hbuf, const int* __restrict__ cnt, const int* __restrict__ poff,
    const int* __restrict__ pairRowC, const float* __restrict__ pairGateC,
    const float* __restrict__ g1, const float* __restrict__ be1,
    const float* __restrict__ W2, const float* __restrict__ b2,
    float* __restrict__ y)
{
    int p = blockIdx.x;
    if (p >= poff[N_EXP]) return;
    int e = 0;
    while (e < N_EXP - 1 && p >= poff[e + 1]) ++e;
    if (p - poff[e] >= cnt[e * CNT_STRIDE]) return;   // padding row

    int row = pairRowC[p];
    float gate = pairGateC[p];
    int tid = threadIdx.x;
    int w = tid >> 6;
    const __hip_bfloat16* hr = hbuf + (long)p * H_DIM;

    union { short4v s; __hip_bfloat16 h[4]; } hv;
    hv.s = ((const short4v*)hr)[tid];
    float v[4];
    float sum = 0.f, sumsq = 0.f;
#pragma unroll
    for (int k = 0; k < 4; ++k) {
        v[k] = __bfloat162float(hv.h[k]);
        sum += v[k];
        sumsq += v[k] * v[k];
    }
#pragma unroll
    for (int off = 32; off > 0; off >>= 1) {
        sum += __shfl_down(sum, off);
        sumsq += __shfl_down(sumsq, off);
    }
    __shared__ float rs[4], rq[4];
    if ((tid & 63) == 0) { rs[w] = sum; rq[w] = sumsq; }
    __syncthreads();
    float tot = rs[0] + rs[1] + rs[2] + rs[3];
    float totq = rq[0] + rq[1] + rq[2] + rq[3];
    float mu = tot * (1.f / H_DIM);
    float var = totq * (1.f / H_DIM) - mu * mu;
    float rstd = rsqrtf(var + LN_EPS);

    float4 gv = ((const float4*)(g1 + e * H_DIM))[tid];
    float4 bv = ((const float4*)(be1 + e * H_DIM))[tid];
    float4 wv = ((const float4*)(W2 + e * H_DIM))[tid];
    float z;
    {
        float hn0 = fmaxf((v[0] - mu) * rstd * gv.x + bv.x, 0.f);
        float hn1 = fmaxf((v[1] - mu) * rstd * gv.y + bv.y, 0.f);
        float hn2 = fmaxf((v[2] - mu) * rstd * gv.z + bv.z, 0.f);
        float hn3 = fmaxf((v[3] - mu) * rstd * gv.w + bv.w, 0.f);
        z = hn0 * wv.x + hn1 * wv.y + hn2 * wv.z + hn3 * wv.w;
    }
#pragma unroll
    for (int off = 32; off > 0; off >>= 1) z += __shfl_down(z, off);
    __syncthreads();
    if ((tid & 63) == 0) rs[w] = z;
    __syncthreads();
    if (tid == 0) {
        float zt = rs[0] + rs[1] + rs[2] + rs[3] + b2[e];
        float o = 1.f / (1.f + expf(-zt));
        atomicAdd(&y[row], gate * o);
    }
}

extern "C" void kernel_launch(void* const* d_in, const int* in_sizes, int n_in,
                              void* d_out, int out_size, void* d_ws, size_t ws_size,
                              hipStream_t stream)
{
    const float* x   = (const float*)d_in[0];
    const float* wg  = (const float*)d_in[1];
    const float* W1  = (const float*)d_in[2];
    const float* b1  = (const float*)d_in[3];
    const float* g1  = (const float*)d_in[4];
    const float* be1 = (const float*)d_in[5];
    const float* W2  = (const float*)d_in[6];
    const float* b2  = (const float*)d_in[7];
    float* y = (float*)d_out;

    char* ws = (char*)d_ws;
    int*   cnt       = (int*)(ws + O_CNT);
    int*   poff      = (int*)(ws + O_POFF);
    int*   cnt2      = (int*)(ws + O_CNT2);
    int*   topIdx    = (int*)(ws + O_TOPI);
    float* topGate   = (float*)(ws + O_TOPG);
    int*   pairRowC  = (int*)(ws + O_PROWC);
    float* pairGateC = (float*)(ws + O_PGATEC);
    __hip_bfloat16* xg   = (__hip_bfloat16*)(ws + O_XG);
    __hip_bfloat16* w1t  = (__hip_bfloat16*)(ws + O_W1T);
    __hip_bfloat16* hbuf = (__hip_bfloat16*)(ws + O_HBUF);

    hipMemsetAsync(cnt, 0, 512, stream);
    hipMemsetAsync(cnt2, 0, 512, stream);
    hipMemsetAsync(y, 0, (size_t)out_size * sizeof(float), stream);

    gating_kernel<<<B_ROWS / 4, 256, 0, stream>>>(x, wg, topIdx, topGate);
    hist_kernel<<<B_ROWS / 256, 256, 0, stream>>>(topIdx, cnt);
    offsets_kernel<<<1, 64, 0, stream>>>(cnt, poff);
    scatter_kernel<<<B_ROWS / 256, 256, 0, stream>>>(topIdx, topGate, poff, cnt2,
                                                     pairRowC, pairGateC);
    w1_transpose_kernel<<<dim3(38, 32, 8), dim3(32, 8), 0, stream>>>(W1, w1t);
    gather_kernel<<<CAP, 256, 0, stream>>>(x, cnt, poff, pairRowC, xg);
    gemm_kernel<<<dim3(N_TILES, 8), 256, 0, stream>>>(xg, w1t, b1, poff, hbuf);
    ln_head_kernel<<<CAP, 256, 0, stream>>>(hbuf, cnt, poff, pairRowC, pairGateC,
                                            g1, be1, W2, b2, y);
}